// Round 15
// baseline (209.895 us; speedup 1.0000x reference)
//
#include <hip/hip_runtime.h>
#include <math.h>

#define NTOK 16384
#define DDIM 2048
#define NEXP 64
#define MT   64                  // tokens per block (= lanes of a wave)
#define KSPLIT 8
#define KRANGE (DDIM / KSPLIT)   // 256
#define KC   32                  // k per LDS chunk
#define NCH  (KRANGE / KC)       // 8

// ws layout (floats): [0..63] f counts, [64..127] P sums, [128] sum lse^2,
// [PART_OFF ...] partial logits [KSPLIT][NTOK][NEXP],
// [WT_OFF ...] transposed W [4 groups][DDIM][16]
#define PART_OFF 256
#define WT_OFF   (PART_OFF + KSPLIT * NTOK * NEXP)

// T3+T4 on the r12 flat-GEMM: 3-deep LDS pipeline, counted vmcnt (never 0
// mid-loop), raw s_barrier (no compiler fence -> no auto vmcnt(0) drain).
// Wave = 64 tokens x 16 experts; W rows wave-uniform -> s_load (scalar).
// Staging: 2 gload16/thread/chunk; at the top of chunk c the wave has
// chunks c+1,c+2 in flight (4 loads) -> s_waitcnt vmcnt(4) completes
// chunk c for THIS wave; since every wave does so before signaling
// barrier 1, the whole buffer is consistent after the barrier (m201).
//
// x tile [64 rows][32 floats]: store slot (row, granule p) holds global
// granule p ^ (row&7); lane reads row=lane, slot granule s2^(lane&7) ->
// 8 granule-classes x 4 dwords = 8 dwords/bank (b128 service optimum).

__device__ __forceinline__ void gload16(const float* g, const float* lds) {
    __builtin_amdgcn_global_load_lds(
        (const __attribute__((address_space(1))) unsigned int*)g,
        (__attribute__((address_space(3))) unsigned int*)lds, 16, 0, 0);
}

// prep: zero the accumulators and build wt[g][k][j] = W[k][g*16+j]
__global__ __launch_bounds__(256) void prep_wt(
    const float* __restrict__ W, float* __restrict__ ws)
{
    const int i = blockIdx.x * 256 + threadIdx.x;   // 0 .. 131071
    if (blockIdx.x == 0 && threadIdx.x < 129) ws[threadIdx.x] = 0.0f;
    const int k = i >> 6, e = i & 63;
    ws[WT_OFF + (size_t)(e >> 4) * (DDIM * 16) + k * 16 + (e & 15)] = W[i];
}

__global__ __launch_bounds__(256, 8) void gemm_part(
    const float* __restrict__ x, const float* __restrict__ wt,
    float* __restrict__ pws)
{
    __shared__ __align__(16) float xb[3][MT * KC];   // 3 x 8 KB

    const int tid  = threadIdx.x;
    const int tb   = blockIdx.x & (NTOK / MT - 1);  // token block 0..255
    const int s    = blockIdx.x >> 8;               // k-split 0..7
    const int tok0 = tb * MT;
    const int kb   = s * KRANGE;

    const int lane = tid & 63;                       // token within block
    const int g    = __builtin_amdgcn_readfirstlane(tid >> 6); // expert group

    // staging: slot o = u*1024 + tid*4 floats -> row = u*32 + (tid>>3),
    // granule p = tid&7; global granule = p ^ ((tid>>3)&7)  (u-invariant)
    const int srow = tid >> 3;                       // + u*32
    const int gcol = (((tid & 7) ^ ((tid >> 3) & 7))) << 2;
    const float* xsrc = x + (size_t)(tok0 + srow) * DDIM + kb + gcol;

    float acc[16];
    #pragma unroll
    for (int j = 0; j < 16; ++j) acc[j] = 0.0f;

    const int l7    = lane & 7;
    const int xbase = lane * KC;                     // lane's row (floats)
    const float* wks = wt + (size_t)g * (DDIM * 16) + (size_t)kb * 16;

    // prologue: stage chunks 0,1,2 into buffers 0,1,2 (6 loads in flight)
    #pragma unroll
    for (int p = 0; p < 3; ++p) {
        gload16(xsrc + p * KC,                     &xb[p][tid * 4]);
        gload16(xsrc + p * KC + (size_t)32 * DDIM, &xb[p][1024 + tid * 4]);
    }

    float* b0 = &xb[0][0];
    float* b1 = &xb[1][0];
    float* b2 = &xb[2][0];

    #pragma unroll 1
    for (int c = 0; c < NCH; ++c) {
        // counted wait: drain THIS wave's chunk-c loads, keep c+1,c+2 in flight
        if (c <= NCH - 3)      asm volatile("s_waitcnt vmcnt(4)" ::: "memory");
        else if (c == NCH - 2) asm volatile("s_waitcnt vmcnt(2)" ::: "memory");
        else                   asm volatile("s_waitcnt vmcnt(0)" ::: "memory");
        __builtin_amdgcn_sched_barrier(0);
        __builtin_amdgcn_s_barrier();          // all waves: chunk c resident
        __builtin_amdgcn_sched_barrier(0);

        const float* cur = b0;
        const float* wkc = wks + (size_t)c * KC * 16;   // contiguous W chunk

        #pragma unroll
        for (int h = 0; h < 2; ++h) {          // half-chunks: 16 k each
            float xv[4][4];
            #pragma unroll
            for (int s2 = 0; s2 < 4; ++s2)
                *(float4*)xv[s2] = *(const float4*)
                    &cur[xbase + ((((h << 2) + s2) ^ l7) << 2)];
            #pragma unroll
            for (int s2 = 0; s2 < 4; ++s2) {
                #pragma unroll
                for (int r = 0; r < 4; ++r) {  // k ascending per acc element
                    const float* wrow =
                        wkc + (size_t)((((h << 2) + s2) << 2) + r) * 16;
                    #pragma unroll
                    for (int j = 0; j < 16; ++j)   // wrow[j]: SGPR operand
                        acc[j] = fmaf(xv[s2][r], wrow[j], acc[j]);
                }
            }
        }

        __builtin_amdgcn_sched_barrier(0);
        __builtin_amdgcn_s_barrier();          // all waves done reading cur
        __builtin_amdgcn_sched_barrier(0);
        if (c + 3 < NCH) {                     // refill the just-read buffer
            const float* src = xsrc + (c + 3) * KC;
            gload16(src,                     &b0[tid * 4]);
            gload16(src + (size_t)32 * DDIM, &b0[1024 + tid * 4]);
        }
        float* t = b0; b0 = b1; b1 = b2; b2 = t;   // rotate
    }

    // store partial logits pws[s][tok][e]
    float* pb = pws + ((size_t)s * NTOK + tok0) * NEXP + (size_t)lane * NEXP
              + g * 16;
    #pragma unroll
    for (int q = 0; q < 4; ++q)
        *(float4*)&pb[q * 4] = *(float4*)&acc[q * 4];
}

#define ETOK 64   // tokens per epilogue block

__global__ __launch_bounds__(256) void epilogue(
    const float* __restrict__ pws, const float* __restrict__ bias,
    float* __restrict__ out, float* __restrict__ acc_g)
{
    __shared__ int   f_loc[NEXP];
    __shared__ float p_loc[NEXP];
    __shared__ float z_loc;

    const int tid = threadIdx.x;
    const int tx  = tid & 15;         // expert group: 4tx..4tx+3
    const int tg  = tid >> 4;         // token slot 0..15
    const int e0  = tx * 4;

    if (tid < NEXP) { f_loc[tid] = 0; p_loc[tid] = 0.0f; }
    if (tid == 0) z_loc = 0.0f;
    __syncthreads();

    float bb[4];
    *(float4*)bb = *(const float4*)&bias[e0];

    float pacc[4] = {0.f, 0.f, 0.f, 0.f};
    float zacc = 0.0f;

    for (int it = 0; it < ETOK / 16; ++it) {
        const int gt = blockIdx.x * ETOK + it * 16 + tg;

        // sum 8 partials in fixed ascending-s order, then + bias
        float l[4];
        {
            const size_t ro = (size_t)gt * NEXP + e0;
            float4 q[KSPLIT];
            #pragma unroll
            for (int sp = 0; sp < KSPLIT; ++sp)
                q[sp] = *(const float4*)&pws[(size_t)sp * NTOK * NEXP + ro];
            float a0 = q[0].x, a1 = q[0].y, a2 = q[0].z, a3 = q[0].w;
            #pragma unroll
            for (int sp = 1; sp < KSPLIT; ++sp) {
                a0 += q[sp].x; a1 += q[sp].y; a2 += q[sp].z; a3 += q[sp].w;
            }
            l[0] = a0 + bb[0]; l[1] = a1 + bb[1];
            l[2] = a2 + bb[2]; l[3] = a3 + bb[3];
        }

        // local top-2 (stable: ascending e, strict >)
        float v1 = l[0], v2 = -INFINITY;
        int   i1 = e0,   i2 = 0x7fffffff;
        #pragma unroll
        for (int j = 1; j < 4; ++j) {
            float v = l[j]; int e = e0 + j;
            if (v > v1)      { v2 = v1; i2 = i1; v1 = v; i1 = e; }
            else if (v > v2) { v2 = v;  i2 = e; }
        }
        // merge across the 16 lanes of this token (value desc, idx asc)
        #pragma unroll
        for (int off = 1; off < 16; off <<= 1) {
            float o1 = __shfl_xor(v1, off, 16); int oi1 = __shfl_xor(i1, off, 16);
            float o2 = __shfl_xor(v2, off, 16); int oi2 = __shfl_xor(i2, off, 16);
            if (o1 > v1 || (o1 == v1 && oi1 < i1)) {
                float cs = v1; int ci = i1;
                v1 = o1; i1 = oi1;
                if (cs > o2 || (cs == o2 && ci < oi2)) { v2 = cs; i2 = ci;  }
                else                                   { v2 = o2; i2 = oi2; }
            } else {
                if (o1 > v2 || (o1 == v2 && oi1 < i2)) { v2 = o1; i2 = oi1; }
            }
        }
        const float mx = v1;

        float sden[4], dsum = 0.0f;
        #pragma unroll
        for (int j = 0; j < 4; ++j) { sden[j] = __expf(l[j] - mx); dsum += sden[j]; }
        #pragma unroll
        for (int off = 1; off < 16; off <<= 1) dsum += __shfl_xor(dsum, off, 16);
        const float inv = 1.0f / dsum;

        float zsum = 0.0f;
        #pragma unroll
        for (int j = 0; j < 4; ++j) {
            float pj = sden[j] * inv;
            pacc[j] += pj;
            zsum += __expf(pj);
        }
        #pragma unroll
        for (int off = 1; off < 16; off <<= 1) zsum += __shfl_xor(zsum, off, 16);

        if (tx == 0) {
            const float s2 = __expf(v2 - mx);      // s1 == 1
            const float ci = 1.0f / (1.0f + s2);
            out[2 * gt]     = (float)i1;
            out[2 * gt + 1] = (float)i2;
            out[2 * NTOK + 2 * gt]     = ci;
            out[2 * NTOK + 2 * gt + 1] = s2 * ci;
            atomicAdd(&f_loc[i1], 1);
            float lse = __logf(zsum);
            zacc += lse * lse;
        }
    }

    // z: wave-reduce (only tx==0 lanes carry nonzero), one LDS atomic per wave
    #pragma unroll
    for (int off = 1; off < 64; off <<= 1) zacc += __shfl_xor(zacc, off);
    if ((tid & 63) == 0) atomicAdd(&z_loc, zacc);

    // P: fold token-groups within wave, then LDS
    #pragma unroll
    for (int j = 0; j < 4; ++j) {
        pacc[j] += __shfl_xor(pacc[j], 16);
        pacc[j] += __shfl_xor(pacc[j], 32);
    }
    if ((tid & 63) < 16) {
        #pragma unroll
        for (int j = 0; j < 4; ++j) atomicAdd(&p_loc[e0 + j], pacc[j]);
    }

    __syncthreads();
    if (tid < NEXP) {
        atomicAdd(&acc_g[64 + tid], p_loc[tid]);
        if (f_loc[tid]) atomicAdd(&acc_g[tid], (float)f_loc[tid]);
    }
    if (tid == 0) atomicAdd(&acc_g[128], z_loc);
}

__global__ void gate_finalize(const float* __restrict__ acc, float* __restrict__ out) {
    int e = threadIdx.x;  // 64 threads
    float v = acc[e] * acc[64 + e];
    #pragma unroll
    for (int off = 32; off > 0; off >>= 1) v += __shfl_down(v, off);
    if (e == 0) {
        const float NT = (float)NTOK;
        out[2 * NTOK * 2]     = 0.01f * (v / (float)NEXP) / (NT * NT);
        out[2 * NTOK * 2 + 1] = 0.1f * acc[128] / NT;
    }
}

extern "C" void kernel_launch(void* const* d_in, const int* in_sizes, int n_in,
                              void* d_out, int out_size, void* d_ws, size_t ws_size,
                              hipStream_t stream) {
    const float* x    = (const float*)d_in[0];
    const float* W    = (const float*)d_in[1];
    const float* bias = (const float*)d_in[2];
    float* out = (float*)d_out;
    float* ws  = (float*)d_ws;
    float* pws = ws + PART_OFF;
    float* wts = ws + WT_OFF;

    prep_wt<<<(DDIM * NEXP) / 256, 256, 0, stream>>>(W, ws);
    gemm_part<<<KSPLIT * (NTOK / MT), 256, 0, stream>>>(x, wts, pws);
    epilogue<<<NTOK / ETOK, 256, 0, stream>>>(pws, bias, out, ws);
    gate_finalize<<<1, 64, 0, stream>>>(ws, out);
}

// Round 16
// 90.960 us; speedup vs baseline: 2.3076x; 2.3076x over previous
//
#include <hip/hip_runtime.h>
#include <math.h>

#define NTOK 16384
#define DDIM 2048
#define NEXP 64
#define MT   64                  // tokens per block (= lanes of a wave)
#define KSPLIT 8
#define KRANGE (DDIM / KSPLIT)   // 256
#define KC   64                  // k per LDS chunk (2048-cyc FMA phase)
#define NCH  (KRANGE / KC)       // 4

// ws layout (floats): [0..63] f counts, [64..127] P sums, [128] sum lse^2,
// [PART_OFF ...] partial logits [KSPLIT][NTOK][NEXP]
#define PART_OFF 256

// r12-consolidation: wave = 64 tokens (lane = token) x 16 experts.
// W[k][g*16..g*16+15] is a 64B-aligned wave-uniform slice of the CONTIGUOUS
// W row -> s_load_dwordx16 directly, no transpose needed (scalar pipe, K$).
// x in LDS: 1 ds_read_b128 per 64 FMA-inst. KC=64 -> one __syncthreads
// drain per 2048 FMA-cycles; the staged loads complete well within the
// phase, so the implied vmcnt(0) finds them done (drain ~free).
//
// x tile [64 rows][64 floats] (256 B rows). Granule (16 B) swizzle:
// slot (row, p) holds global granule p ^ (row&7). Lane reads row = lane,
// granule s2 ^ (lane&7): 8 lane-classes x 8 distinct bank-quads =
// 8 dwords/bank (b128 service optimum). Store side (gload16, lane-linear):
// slot o = u*1024 + tid*4 floats -> row = u*16 + (tid>>4), p = tid&15;
// global granule = p ^ (row&7) = (tid&15) ^ ((tid>>4)&7), u-invariant
// ((u*16)&7 == 0). Within each 16-lane row group the XOR permutes the 16
// granules -> still one coalesced 256 B segment per row.

__device__ __forceinline__ void gload16(const float* g, const float* lds) {
    __builtin_amdgcn_global_load_lds(
        (const __attribute__((address_space(1))) unsigned int*)g,
        (__attribute__((address_space(3))) unsigned int*)lds, 16, 0, 0);
}

__global__ void zero_acc(float* acc) {
    int t = threadIdx.x;
    if (t < 129) acc[t] = 0.0f;
}

__global__ __launch_bounds__(256, 8) void gemm_part(
    const float* __restrict__ x, const float* __restrict__ W,
    float* __restrict__ pws)
{
    __shared__ __align__(16) float xb[2][MT * KC];   // 2 x 16 KB

    const int tid  = threadIdx.x;
    const int tb   = blockIdx.x & (NTOK / MT - 1);  // token block 0..255
    const int s    = blockIdx.x >> 8;               // k-split 0..7
    const int tok0 = tb * MT;
    const int kb   = s * KRANGE;

    const int lane = tid & 63;                       // token within block
    const int g    = __builtin_amdgcn_readfirstlane(tid >> 6); // expert group

    // staging: 4 gload16/thread/chunk; slot o = u*1024 + tid*4 floats ->
    // row = u*16 + (tid>>4), granule p = tid&15;
    // global granule = p ^ ((tid>>4)&7)   (u-invariant)
    const int srow = tid >> 4;                       // + u*16
    const int gcol = (((tid & 15) ^ ((tid >> 4) & 7))) << 2;
    const float* xsrc = x + (size_t)(tok0 + srow) * DDIM + kb + gcol;

    float acc[16];
    #pragma unroll
    for (int j = 0; j < 16; ++j) acc[j] = 0.0f;

    const int l7    = lane & 7;
    const int xbase = lane * KC;                     // lane's row (floats)
    const float* wks = W + (size_t)kb * NEXP + g * 16; // uniform scalar base

    // prologue: stage chunk 0 into buffer 0
    #pragma unroll
    for (int u = 0; u < 4; ++u)
        gload16(xsrc + (size_t)u * 16 * DDIM, &xb[0][u * 1024 + tid * 4]);

    #pragma unroll 1
    for (int c = 0; c < NCH; ++c) {
        __syncthreads();   // drains vmcnt -> chunk c staged; prev reads done
        const float* cur = xb[c & 1];
        float* nxt       = xb[(c & 1) ^ 1];
        if (c + 1 < NCH) {            // issue next chunk EARLY (T3 2-phase)
            const float* src = xsrc + (c + 1) * KC;
            #pragma unroll
            for (int u = 0; u < 4; ++u)
                gload16(src + (size_t)u * 16 * DDIM, &nxt[u * 1024 + tid * 4]);
        }
        const float* wkc = wks + (size_t)c * KC * NEXP;
        #pragma unroll
        for (int s2 = 0; s2 < KC / 4; ++s2) {
            float xv[4];
            *(float4*)xv = *(const float4*)&cur[xbase + ((s2 ^ l7) << 2)];
            #pragma unroll
            for (int r = 0; r < 4; ++r) {            // k ascending
                const float* wrow = wkc + (size_t)(4 * s2 + r) * NEXP;
                #pragma unroll
                for (int j = 0; j < 16; ++j)         // wrow[j]: SGPR operand
                    acc[j] = fmaf(xv[r], wrow[j], acc[j]);
            }
        }
    }

    // store partial logits pws[s][tok][e]
    float* pb = pws + ((size_t)s * NTOK + tok0) * NEXP + (size_t)lane * NEXP
              + g * 16;
    #pragma unroll
    for (int q = 0; q < 4; ++q)
        *(float4*)&pb[q * 4] = *(float4*)&acc[q * 4];
}

#define ETOK 64   // tokens per epilogue block

__global__ __launch_bounds__(256) void epilogue(
    const float* __restrict__ pws, const float* __restrict__ bias,
    float* __restrict__ out, float* __restrict__ acc_g)
{
    __shared__ int   f_loc[NEXP];
    __shared__ float p_loc[NEXP];
    __shared__ float z_loc;

    const int tid = threadIdx.x;
    const int tx  = tid & 15;         // expert group: 4tx..4tx+3
    const int tg  = tid >> 4;         // token slot 0..15
    const int e0  = tx * 4;

    if (tid < NEXP) { f_loc[tid] = 0; p_loc[tid] = 0.0f; }
    if (tid == 0) z_loc = 0.0f;
    __syncthreads();

    float bb[4];
    *(float4*)bb = *(const float4*)&bias[e0];

    float pacc[4] = {0.f, 0.f, 0.f, 0.f};
    float zacc = 0.0f;

    for (int it = 0; it < ETOK / 16; ++it) {
        const int gt = blockIdx.x * ETOK + it * 16 + tg;

        // sum 8 partials in fixed ascending-s order, then + bias
        float l[4];
        {
            const size_t ro = (size_t)gt * NEXP + e0;
            float4 q[KSPLIT];
            #pragma unroll
            for (int sp = 0; sp < KSPLIT; ++sp)
                q[sp] = *(const float4*)&pws[(size_t)sp * NTOK * NEXP + ro];
            float a0 = q[0].x, a1 = q[0].y, a2 = q[0].z, a3 = q[0].w;
            #pragma unroll
            for (int sp = 1; sp < KSPLIT; ++sp) {
                a0 += q[sp].x; a1 += q[sp].y; a2 += q[sp].z; a3 += q[sp].w;
            }
            l[0] = a0 + bb[0]; l[1] = a1 + bb[1];
            l[2] = a2 + bb[2]; l[3] = a3 + bb[3];
        }

        // local top-2 (stable: ascending e, strict >)
        float v1 = l[0], v2 = -INFINITY;
        int   i1 = e0,   i2 = 0x7fffffff;
        #pragma unroll
        for (int j = 1; j < 4; ++j) {
            float v = l[j]; int e = e0 + j;
            if (v > v1)      { v2 = v1; i2 = i1; v1 = v; i1 = e; }
            else if (v > v2) { v2 = v;  i2 = e; }
        }
        // merge across the 16 lanes of this token (value desc, idx asc)
        #pragma unroll
        for (int off = 1; off < 16; off <<= 1) {
            float o1 = __shfl_xor(v1, off, 16); int oi1 = __shfl_xor(i1, off, 16);
            float o2 = __shfl_xor(v2, off, 16); int oi2 = __shfl_xor(i2, off, 16);
            if (o1 > v1 || (o1 == v1 && oi1 < i1)) {
                float cs = v1; int ci = i1;
                v1 = o1; i1 = oi1;
                if (cs > o2 || (cs == o2 && ci < oi2)) { v2 = cs; i2 = ci;  }
                else                                   { v2 = o2; i2 = oi2; }
            } else {
                if (o1 > v2 || (o1 == v2 && oi1 < i2)) { v2 = o1; i2 = oi1; }
            }
        }
        const float mx = v1;

        float sden[4], dsum = 0.0f;
        #pragma unroll
        for (int j = 0; j < 4; ++j) { sden[j] = __expf(l[j] - mx); dsum += sden[j]; }
        #pragma unroll
        for (int off = 1; off < 16; off <<= 1) dsum += __shfl_xor(dsum, off, 16);
        const float inv = 1.0f / dsum;

        float zsum = 0.0f;
        #pragma unroll
        for (int j = 0; j < 4; ++j) {
            float pj = sden[j] * inv;
            pacc[j] += pj;
            zsum += __expf(pj);
        }
        #pragma unroll
        for (int off = 1; off < 16; off <<= 1) zsum += __shfl_xor(zsum, off, 16);

        if (tx == 0) {
            const float s2 = __expf(v2 - mx);      // s1 == 1
            const float ci = 1.0f / (1.0f + s2);
            out[2 * gt]     = (float)i1;
            out[2 * gt + 1] = (float)i2;
            out[2 * NTOK + 2 * gt]     = ci;
            out[2 * NTOK + 2 * gt + 1] = s2 * ci;
            atomicAdd(&f_loc[i1], 1);
            float lse = __logf(zsum);
            zacc += lse * lse;
        }
    }

    // z: wave-reduce (only tx==0 lanes carry nonzero), one LDS atomic per wave
    #pragma unroll
    for (int off = 1; off < 64; off <<= 1) zacc += __shfl_xor(zacc, off);
    if ((tid & 63) == 0) atomicAdd(&z_loc, zacc);

    // P: fold token-groups within wave, then LDS
    #pragma unroll
    for (int j = 0; j < 4; ++j) {
        pacc[j] += __shfl_xor(pacc[j], 16);
        pacc[j] += __shfl_xor(pacc[j], 32);
    }
    if ((tid & 63) < 16) {
        #pragma unroll
        for (int j = 0; j < 4; ++j) atomicAdd(&p_loc[e0 + j], pacc[j]);
    }

    __syncthreads();
    if (tid < NEXP) {
        atomicAdd(&acc_g[64 + tid], p_loc[tid]);
        if (f_loc[tid]) atomicAdd(&acc_g[tid], (float)f_loc[tid]);
    }
    if (tid == 0) atomicAdd(&acc_g[128], z_loc);
}

__global__ void gate_finalize(const float* __restrict__ acc, float* __restrict__ out) {
    int e = threadIdx.x;  // 64 threads
    float v = acc[e] * acc[64 + e];
    #pragma unroll
    for (int off = 32; off > 0; off >>= 1) v += __shfl_down(v, off);
    if (e == 0) {
        const float NT = (float)NTOK;
        out[2 * NTOK * 2]     = 0.01f * (v / (float)NEXP) / (NT * NT);
        out[2 * NTOK * 2 + 1] = 0.1f * acc[128] / NT;
    }
}

extern "C" void kernel_launch(void* const* d_in, const int* in_sizes, int n_in,
                              void* d_out, int out_size, void* d_ws, size_t ws_size,
                              hipStream_t stream) {
    const float* x    = (const float*)d_in[0];
    const float* W    = (const float*)d_in[1];
    const float* bias = (const float*)d_in[2];
    float* out = (float*)d_out;
    float* ws  = (float*)d_ws;
    float* pws = ws + PART_OFF;

    zero_acc<<<1, 256, 0, stream>>>(ws);
    gemm_part<<<KSPLIT * (NTOK / MT), 256, 0, stream>>>(x, W, pws);
    epilogue<<<NTOK / ETOK, 256, 0, stream>>>(pws, bias, out, ws);
    gate_finalize<<<1, 64, 0, stream>>>(ws, out);
}

// Round 18
// 69.796 us; speedup vs baseline: 3.0073x; 1.3032x over previous
//
#include <hip/hip_runtime.h>
#include <math.h>

#define NTOK 16384
#define DDIM 2048
#define NEXP 64
#define MT   16                  // tokens per block
#define KCH  256                 // k per chunk
#define NCH  (DDIM / KCH)        // 8

// ws layout: [0..128] acc (f counts / P sums / z). floats.
// [WF_OFF ...] W fragments: bf16[3 levels][4 groups][64 ksteps][64 lanes][8]
#define ACC_N  129
#define WF_OFF 256
#define VSTRIDE ((size_t)4 * 64 * 64 * 8)   // ushorts per level

typedef __attribute__((ext_vector_type(8))) short short8_t;
typedef __attribute__((ext_vector_type(4))) float f32x4;

// exact RNE fp32->bf16 (bit trick), and back
__device__ __forceinline__ unsigned short f2bf(float f) {
    unsigned int u = __float_as_uint(f);
    u += 0x7fffu + ((u >> 16) & 1u);
    return (unsigned short)(u >> 16);
}
__device__ __forceinline__ float bf2f(unsigned short s) {
    return __uint_as_float(((unsigned int)s) << 16);
}

// prep: zero acc; split W into 3 exact bf16 levels, stored in MFMA B-fragment
// order: wf[v][g][ks][lane][j] = level_v of W[ks*32 + (lane>>4)*8 + j][g*16 + (lane&15)]
__global__ __launch_bounds__(256) void prep(
    const float* __restrict__ W, float* __restrict__ ws)
{
    const int i = blockIdx.x * 256 + threadIdx.x;   // 0..131071
    if (blockIdx.x == 0 && threadIdx.x < ACC_N) ws[threadIdx.x] = 0.0f;
    const int k = i >> 6, e = i & 63;
    const float v = W[i];
    unsigned short h = f2bf(v);
    float r1 = v - bf2f(h);                 // exact (Sterbenz)
    unsigned short m = f2bf(r1);
    unsigned short l = f2bf(r1 - bf2f(m));  // exact
    unsigned short* wf = (unsigned short*)(ws + WF_OFF);
    const int g = e >> 4, ks = k >> 5;
    const int lane = (((k >> 3) & 3) << 4) | (e & 15);
    const int j = k & 7;
    const size_t base = ((((size_t)g * 64) + ks) * 64 + lane) * 8 + j;
    wf[base] = h;
    wf[VSTRIDE + base] = m;
    wf[2 * VSTRIDE + base] = l;
}

// Fused MFMA gate: 16 tokens/block, full K, all 64 experts (4 waves x 16).
// x split exactly into bf16 {hi,mid,lo} on the fly; 6 products/k-step ->
// logit error ~7e-9 << the ~1e-6 split-reorder noise already passing.
//
// A-tile LDS (per level) [16 rows][256 k] bf16: granule(8 elems) slot =
// gr ^ (row&7) -> frag read (lanes 0-15 = rows 0-15, same gr) spreads over
// 8 bank-quads x 2 rows = 8 dwords/bank (b128 optimum). Conversion writes
// use the same XOR (row = tid>>4, gr = 2(tid&15)+{0,1}).
__global__ __launch_bounds__(256, 4) void gate_fused(
    const float* __restrict__ x, const unsigned short* __restrict__ wf,
    const float* __restrict__ bias, float* __restrict__ out,
    float* __restrict__ acc_g)
{
    __shared__ __align__(16) unsigned short xh[MT * KCH];   // 8 KB
    __shared__ __align__(16) unsigned short xm_[MT * KCH];  // 8 KB
    __shared__ __align__(16) unsigned short xl_[MT * KCH];  // 8 KB
    __shared__ float logits[MT][68];
    __shared__ int   f_loc[NEXP];
    __shared__ float p_loc[NEXP];
    __shared__ float z_loc;

    const int tid  = threadIdx.x;
    const int tok0 = blockIdx.x * MT;
    const int lane = tid & 63;
    const int g    = __builtin_amdgcn_readfirstlane(tid >> 6);  // expert group

    if (tid < NEXP) { f_loc[tid] = 0; p_loc[tid] = 0.0f; }
    if (tid == 0) z_loc = 0.0f;

    // staging: thread owns row = tid>>4, 16 consecutive floats at col group
    const int srow = tid >> 4;
    const int scg  = tid & 15;
    const float* xs = x + (size_t)(tok0 + srow) * DDIM + scg * 16;
    const int wbase = srow * KCH;                       // ushort row base
    const int s0 = (((scg * 2)     ^ (srow & 7))) * 8;  // swizzled granules
    const int s1 = (((scg * 2 + 1) ^ (srow & 7))) * 8;

    // A-fragment addressing: lane holds A[row=lane&15][k=(lane>>4)*8+j]
    const int arow  = lane & 15;
    const int akq   = lane >> 4;
    const int abase = arow * KCH;

    f32x4 acc = {0.0f, 0.0f, 0.0f, 0.0f};

    // preload chunk 0 (T14: loads live in regs across the barrier)
    float4 pv0 = *(const float4*)(xs + 0);
    float4 pv1 = *(const float4*)(xs + 4);
    float4 pv2 = *(const float4*)(xs + 8);
    float4 pv3 = *(const float4*)(xs + 12);

    #pragma unroll 1
    for (int c = 0; c < NCH; ++c) {
        __syncthreads();           // prev MFMA phase done reading A-tiles
        float xv[16];
        *(float4*)&xv[0]  = pv0; *(float4*)&xv[4]  = pv1;
        *(float4*)&xv[8]  = pv2; *(float4*)&xv[12] = pv3;
        unsigned short th[16], tm[16], tl[16];
        #pragma unroll
        for (int i = 0; i < 16; ++i) {
            float f = xv[i];
            th[i] = f2bf(f);
            float r = f - bf2f(th[i]);      // exact
            tm[i] = f2bf(r);
            tl[i] = f2bf(r - bf2f(tm[i]));  // exact
        }
        *(short8_t*)&xh[wbase + s0]  = *(short8_t*)&th[0];
        *(short8_t*)&xh[wbase + s1]  = *(short8_t*)&th[8];
        *(short8_t*)&xm_[wbase + s0] = *(short8_t*)&tm[0];
        *(short8_t*)&xm_[wbase + s1] = *(short8_t*)&tm[8];
        *(short8_t*)&xl_[wbase + s0] = *(short8_t*)&tl[0];
        *(short8_t*)&xl_[wbase + s1] = *(short8_t*)&tl[8];
        __syncthreads();           // A-tiles visible
        if (c + 1 < NCH) {         // issue next chunk's loads under MFMA
            const float* xn = xs + (c + 1) * KCH;
            pv0 = *(const float4*)(xn + 0);
            pv1 = *(const float4*)(xn + 4);
            pv2 = *(const float4*)(xn + 8);
            pv3 = *(const float4*)(xn + 12);
        }
        // MFMA phase: 8 k-steps x 6 products
        const unsigned short* wb0 =
            wf + ((((size_t)g * 64) + c * 8) * 64 + lane) * 8;
        #pragma unroll
        for (int s = 0; s < 8; ++s) {
            const int slot = (((s * 4 + akq) ^ (arow & 7))) * 8;
            short8_t ah = *(const short8_t*)&xh[abase + slot];
            short8_t am = *(const short8_t*)&xm_[abase + slot];
            short8_t al = *(const short8_t*)&xl_[abase + slot];
            const unsigned short* wb = wb0 + (size_t)s * 64 * 8;
            short8_t bh = *(const short8_t*)&wb[0];
            short8_t bm = *(const short8_t*)&wb[VSTRIDE];
            short8_t bl = *(const short8_t*)&wb[2 * VSTRIDE];
            acc = __builtin_amdgcn_mfma_f32_16x16x32_bf16(ah, bh, acc, 0, 0, 0);
            acc = __builtin_amdgcn_mfma_f32_16x16x32_bf16(ah, bm, acc, 0, 0, 0);
            acc = __builtin_amdgcn_mfma_f32_16x16x32_bf16(am, bh, acc, 0, 0, 0);
            acc = __builtin_amdgcn_mfma_f32_16x16x32_bf16(ah, bl, acc, 0, 0, 0);
            acc = __builtin_amdgcn_mfma_f32_16x16x32_bf16(am, bm, acc, 0, 0, 0);
            acc = __builtin_amdgcn_mfma_f32_16x16x32_bf16(al, bh, acc, 0, 0, 0);
        }
    }

    // C layout (m89): col = lane&15 (expert-in-group), row = (lane>>4)*4+reg
    #pragma unroll
    for (int r = 0; r < 4; ++r)
        logits[akq * 4 + r][g * 16 + arow] = acc[r];
    __syncthreads();

    // ---- fused epilogue (r3-verified logic), 16 lanes per token ----
    const int tx = tid & 15;          // expert group of 4
    const int tg = tid >> 4;          // token 0..15
    const int e0 = tx * 4;
    const int gt = tok0 + tg;

    float bb[4];
    *(float4*)bb = *(const float4*)&bias[e0];
    float l[4];
    {
        float4 lv = *(const float4*)&logits[tg][e0];
        l[0] = lv.x + bb[0]; l[1] = lv.y + bb[1];
        l[2] = lv.z + bb[2]; l[3] = lv.w + bb[3];
    }

    // local top-2 (stable: ascending e, strict >)
    float v1 = l[0], v2 = -INFINITY;
    int   i1 = e0,   i2 = 0x7fffffff;
    #pragma unroll
    for (int j = 1; j < 4; ++j) {
        float v = l[j]; int e = e0 + j;
        if (v > v1)      { v2 = v1; i2 = i1; v1 = v; i1 = e; }
        else if (v > v2) { v2 = v;  i2 = e; }
    }
    // merge across the 16 lanes of this token (value desc, idx asc)
    #pragma unroll
    for (int off = 1; off < 16; off <<= 1) {
        float o1 = __shfl_xor(v1, off, 16); int oi1 = __shfl_xor(i1, off, 16);
        float o2 = __shfl_xor(v2, off, 16); int oi2 = __shfl_xor(i2, off, 16);
        if (o1 > v1 || (o1 == v1 && oi1 < i1)) {
            float cs = v1; int ci = i1;
            v1 = o1; i1 = oi1;
            if (cs > o2 || (cs == o2 && ci < oi2)) { v2 = cs; i2 = ci;  }
            else                                   { v2 = o2; i2 = oi2; }
        } else {
            if (o1 > v2 || (o1 == v2 && oi1 < i2)) { v2 = o1; i2 = oi1; }
        }
    }
    const float mx = v1;

    float sden[4], dsum = 0.0f;
    #pragma unroll
    for (int j = 0; j < 4; ++j) { sden[j] = __expf(l[j] - mx); dsum += sden[j]; }
    #pragma unroll
    for (int off = 1; off < 16; off <<= 1) dsum += __shfl_xor(dsum, off, 16);
    const float inv = 1.0f / dsum;

    float p[4], zsum = 0.0f;
    #pragma unroll
    for (int j = 0; j < 4; ++j) {
        p[j] = sden[j] * inv;
        zsum += __expf(p[j]);
    }
    #pragma unroll
    for (int off = 1; off < 16; off <<= 1) zsum += __shfl_xor(zsum, off, 16);

    float zacc = 0.0f;
    if (tx == 0) {
        const float s2 = __expf(v2 - mx);      // s1 == 1
        const float ci = 1.0f / (1.0f + s2);
        out[2 * gt]     = (float)i1;
        out[2 * gt + 1] = (float)i2;
        out[2 * NTOK + 2 * gt]     = ci;
        out[2 * NTOK + 2 * gt + 1] = s2 * ci;
        atomicAdd(&f_loc[i1], 1);
        float lse = __logf(zsum);
        zacc = lse * lse;
    }

    // z: wave-reduce (only tx==0 lanes nonzero), one LDS atomic per wave
    #pragma unroll
    for (int off = 1; off < 64; off <<= 1) zacc += __shfl_xor(zacc, off);
    if ((tid & 63) == 0) atomicAdd(&z_loc, zacc);

    // P: fold token-groups within wave, then LDS
    #pragma unroll
    for (int j = 0; j < 4; ++j) {
        p[j] += __shfl_xor(p[j], 16);
        p[j] += __shfl_xor(p[j], 32);
    }
    if ((tid & 63) < 16) {
        #pragma unroll
        for (int j = 0; j < 4; ++j) atomicAdd(&p_loc[e0 + j], p[j]);
    }

    __syncthreads();
    if (tid < NEXP) {
        atomicAdd(&acc_g[64 + tid], p_loc[tid]);
        if (f_loc[tid]) atomicAdd(&acc_g[tid], (float)f_loc[tid]);
    }
    if (tid == 0) atomicAdd(&acc_g[128], z_loc);
}

__global__ void gate_finalize(const float* __restrict__ acc, float* __restrict__ out) {
    int e = threadIdx.x;  // 64 threads
    float v = acc[e] * acc[64 + e];
    #pragma unroll
    for (int off = 32; off > 0; off >>= 1) v += __shfl_down(v, off);
    if (e == 0) {
        const float NT = (float)NTOK;
        out[2 * NTOK * 2]     = 0.01f * (v / (float)NEXP) / (NT * NT);
        out[2 * NTOK * 2 + 1] = 0.1f * acc[128] / NT;
    }
}

extern "C" void kernel_launch(void* const* d_in, const int* in_sizes, int n_in,
                              void* d_out, int out_size, void* d_ws, size_t ws_size,
                              hipStream_t stream) {
    const float* x    = (const float*)d_in[0];
    const float* W    = (const float*)d_in[1];
    const float* bias = (const float*)d_in[2];
    float* out = (float*)d_out;
    float* ws  = (float*)d_ws;
    const unsigned short* wfrag = (const unsigned short*)(ws + WF_OFF);

    prep<<<(DDIM * NEXP) / 256, 256, 0, stream>>>(W, ws);
    gate_fused<<<NTOK / MT, 256, 0, stream>>>(x, wfrag, bias, out, ws);
    gate_finalize<<<1, 64, 0, stream>>>(ws, out);
}